// Round 6
// baseline (11.888 us; speedup 1.0000x reference)
//
#include <hip/hip_runtime.h>

typedef float floatx4 __attribute__((ext_vector_type(4)));

#define NB 8
#define T_IN 512
#define D 384
#define D4 96            // D/4
#define T_MEL 3584
#define MEL_MAX 2048

#define FRAMES_PER_BLOCK 16
#define GB_PER_BATCH (MEL_MAX / FRAMES_PER_BLOCK)   // 128
#define GATHER_BLOCKS (NB * GB_PER_BATCH)           // 1024
#define PITCH_BLOCKS  NB                            // 1 block/batch, 2 tokens/thread

#define DEC_OFF  ((size_t)NB * MEL_MAX * D)         // dec_lens offset in out
#define PITCH_OFF (DEC_OFF + NB)                    // pitch_avg offset in out

// ---------------------------------------------------------------------------
// Single fused kernel, 2 barriers, no binary search. Every block redundantly
// scans its batch's 512 durations (2 KB, L2-hot); each thread then holds its
// TWO tokens' [start,end) in registers (PACE==1.0 -> reps == dur).
//   blocks [0,1024):    scatter token ids into a 16-frame window map, then
//                       stream 16 frames x 96 float4 of enc_rep.
//   blocks [1024,1032): pitch averages (2 tokens/thread, float2 store)
//                       + dec_lens.
// ---------------------------------------------------------------------------
__global__ __launch_bounds__(256) void fp_fused_kernel(
    const int* __restrict__ dur,
    const floatx4* __restrict__ enc4,
    const float* __restrict__ pitch,
    float* __restrict__ out)
{
    const int bid = blockIdx.x;
    const int tid = threadIdx.x;
    const bool isPitch = bid >= GATHER_BLOCKS;
    const int b = isPitch ? (bid - GATHER_BLOCKS) : (bid >> 7);

    __shared__ int s_wsum[4];
    __shared__ int s_map[FRAMES_PER_BLOCK];

    // map init (before the scan barrier)
    if (!isPitch && tid < FRAMES_PER_BLOCK) s_map[tid] = -1;

    // ---- scan: 2 durations per thread, wave shuffle scan + wave offsets ----
    const int2 dd = ((const int2*)(dur + b * T_IN))[tid];   // dur[2t], dur[2t+1]
    int x = dd.x + dd.y;
    #pragma unroll
    for (int off = 1; off < 64; off <<= 1) {
        int y = __shfl_up(x, off, 64);
        if ((tid & 63) >= off) x += y;
    }
    if ((tid & 63) == 63) s_wsum[tid >> 6] = x;
    __syncthreads();
    int woff = 0, total = 0;
    #pragma unroll
    for (int i = 0; i < 4; ++i) {
        int v = s_wsum[i];
        if (i < (tid >> 6)) woff += v;
        total += v;
    }
    const int end1   = woff + x;        // inclusive end of token 2tid+1
    const int start1 = end1 - dd.y;
    const int start0 = start1 - dd.x;   // token 2tid: [start0, start1)

    if (!isPitch) {
        const int f0 = (bid & (GB_PER_BATCH - 1)) * FRAMES_PER_BLOCK;
        const int f1 = f0 + FRAMES_PER_BLOCK;
        // scatter: each frame belongs to exactly one token -> no conflicts
        {
            const int sA = start0 > f0 ? start0 : f0;
            const int eA = start1 < f1 ? start1 : f1;
            for (int f = sA; f < eA; ++f) s_map[f - f0] = 2 * tid;
            const int sB = start1 > f0 ? start1 : f0;
            const int eB = end1 < f1 ? end1 : f1;
            for (int f = sB; f < eB; ++f) s_map[f - f0] = 2 * tid + 1;
        }
        __syncthreads();

        const floatx4* erow = enc4 + (size_t)b * T_IN * D4;
        floatx4* orow = (floatx4*)out + ((size_t)b * MEL_MAX + f0) * D4;
        #pragma unroll
        for (int it = 0; it < (FRAMES_PER_BLOCK * D4) / 256; ++it) {  // 6
            const int idx = it * 256 + tid;        // 0..1535 contiguous
            const int fl  = idx / D4;
            const int d4  = idx - fl * D4;
            const int tok = s_map[fl];
            floatx4 v = (floatx4)(0.0f);
            if (tok >= 0) v = erow[(size_t)tok * D4 + d4];
            orow[idx] = v;
        }
    } else {
        if (tid == 0)
            out[DEC_OFF + b] = (float)(total < MEL_MAX ? total : MEL_MAX);
        const float* p = pitch + (size_t)b * T_MEL;
        float2 r;
        {
            float acc = 0.0f; int cnt = 0;
            for (int m = start0; m < start1; ++m) {
                float v = p[m]; acc += v; cnt += (v != 0.0f) ? 1 : 0;
            }
            r.x = cnt ? acc / (float)cnt : 0.0f;
        }
        {
            float acc = 0.0f; int cnt = 0;
            for (int m = start1; m < end1; ++m) {
                float v = p[m]; acc += v; cnt += (v != 0.0f) ? 1 : 0;
            }
            r.y = cnt ? acc / (float)cnt : 0.0f;
        }
        ((float2*)(out + PITCH_OFF + b * T_IN))[tid] = r;
    }
}

extern "C" void kernel_launch(void* const* d_in, const int* in_sizes, int n_in,
                              void* d_out, int out_size, void* d_ws, size_t ws_size,
                              hipStream_t stream) {
    const float* enc   = (const float*)d_in[0];
    const int*   dur   = (const int*)d_in[1];
    const float* pitch = (const float*)d_in[2];
    float* out = (float*)d_out;

    fp_fused_kernel<<<GATHER_BLOCKS + PITCH_BLOCKS, 256, 0, stream>>>(
        dur, (const floatx4*)enc, pitch, out);
}